// Round 1
// baseline (177.327 us; speedup 1.0000x reference)
//
#include <hip/hip_runtime.h>

// MoE: out[b,:] = sum_e softmax(gate(x))[b,e] * (W3_e^T @ relu(W2_e^T @ relu(W1_e^T @ x_b + b1) + b2) + b3)
// Tokens-as-N MFMA. L1 uses 16x16x16 f16 (K=7 useful, k=4q+j). L2/L3/gate-L2 use 16x16x32 f16
// with K-permutation pi(q*8+j)=q*4+(j&3)+16*(j>>2) so C/D layout == next layer's B layout
// in-lane (HW-verified across R2-R8: absmax 0.0156).
// R9: one wave owns a whole tile (all 8 experts). Rationale: issue-bound at VALUBusy 51% with
//     4x-redundant gate + per-tile LDS/barrier combine. With 8 experts/wave the L3 rows m=(e,o)
//     fill all 16 acc rows and quad q holds exactly experts {2q,2q+1} -- the same pair the gate
//     bpermute (gsrc) already delivers. Combine collapses to 2x shfl_xor(16/32); gate computed
//     once per tile; NO LDS, NO __syncthreads. Trade: ~220 VGPR -> 2 waves/SIMD (independent
//     waves + 8-way expert ILP hide latency). Y split into two accs to halve the serial
//     MFMA-accumulate chain.

typedef _Float16 half2_t __attribute__((ext_vector_type(2)));
typedef _Float16 half4_t __attribute__((ext_vector_type(4)));
typedef _Float16 half8_t __attribute__((ext_vector_type(8)));
typedef __fp16   fp16v2  __attribute__((ext_vector_type(2)));
typedef float  float4_t __attribute__((ext_vector_type(4)));
typedef float  float2_t __attribute__((ext_vector_type(2)));
typedef int    int2_t   __attribute__((ext_vector_type(2)));
typedef int    int4_t   __attribute__((ext_vector_type(4)));

#define MFMA_K32(A, B, C) __builtin_amdgcn_mfma_f32_16x16x32_f16((A), (B), (C), 0, 0, 0)
#define MFMA_K16(A, B, C) __builtin_amdgcn_mfma_f32_16x16x16f16((A), (B), (C), 0, 0, 0)

static constexpr int E_ = 8, DIN_ = 6, H_ = 32, EPW_ = 8;   // experts per wave (all of them)

union H8U { half2_t h2[4]; half8_t h8; int4_t i4; };
union H4U { half2_t h2[2]; half4_t h4; int2_t i2; };
union HI  { half2_t h; int i; };
union PKU { fp16v2 p; half2_t h; };

__device__ __forceinline__ half2_t pkrtz(float a, float b) {
    PKU u; u.p = __builtin_amdgcn_cvt_pkrtz(a, b);
    return u.h;
}

__device__ __forceinline__ half2_t relu2(half2_t v) {
    const half2_t z = {(_Float16)0.0f, (_Float16)0.0f};
    return __builtin_elementwise_max(v, z);
}

__global__ __launch_bounds__(256, 2)
void moe_kernel(
    const float* __restrict__ x,  const float* __restrict__ W1, const float* __restrict__ b1,
    const float* __restrict__ W2, const float* __restrict__ b2, const float* __restrict__ W3,
    const float* __restrict__ b3, const float* __restrict__ Wg1, const float* __restrict__ bg1,
    const float* __restrict__ Wg2, const float* __restrict__ bg2,
    float* __restrict__ out, int nTiles, int tilesPerWave)
{
    const int tid  = threadIdx.x;
    const int lane = tid & 63;
    const int t    = lane & 15;   // token slot
    const int q    = lane >> 4;   // K-quad / row-quad
    const int gw   = (blockIdx.x << 2) + (tid >> 6);   // global wave id (waves independent)

    const float L2E = 1.44269504f;

    // ---- gate L1 A-fragments (K=16, k=4q+j; slots 0..5 = x features, 6 = bias-as-1.0)
    H4U G1[2];
    #pragma unroll
    for (int f = 0; f < 2; ++f) {
        float v0 = 0.f, v1 = 0.f, v2 = 0.f, v3 = 0.f;
        if (q == 0) {
            v0 = Wg1[0 * H_ + f * 16 + t]; v1 = Wg1[1 * H_ + f * 16 + t];
            v2 = Wg1[2 * H_ + f * 16 + t]; v3 = Wg1[3 * H_ + f * 16 + t];
        } else if (q == 1) {
            v0 = Wg1[4 * H_ + f * 16 + t]; v1 = Wg1[5 * H_ + f * 16 + t];
            v2 = bg1[f * 16 + t];          v3 = 0.f;
        }
        G1[f].h2[0] = pkrtz(v0, v1); G1[f].h2[1] = pkrtz(v2, v3);
    }
    // ---- gate L2 A-fragment (K=32, pi layout), pre-scaled by log2(e) so logits are exp2-ready
    H8U G2;
    #pragma unroll
    for (int p = 0; p < 4; ++p) {
        int c0 = ((p >> 1) << 4) + q * 4 + ((p & 1) << 1);
        float v0 = (t < E_) ? Wg2[c0 * E_ + t] * L2E : 0.f;
        float v1 = (t < E_) ? Wg2[(c0 + 1) * E_ + t] * L2E : 0.f;
        G2.h2[p] = pkrtz(v0, v1);
    }

    // ---- ALL 8 experts: L1 (K16), L2 (K32 pi), L3 (K32 pi, block-diag rows), b2 pairs
    H4U W1F[EPW_][2];
    H8U W2F[EPW_][2], W3F[EPW_], B2R[EPW_];
    #pragma unroll
    for (int e = 0; e < EPW_; ++e) {
        #pragma unroll
        for (int f = 0; f < 2; ++f) {
            float v0 = 0.f, v1 = 0.f, v2 = 0.f, v3 = 0.f;
            const float* We = W1 + (size_t)e * DIN_ * H_ + f * 16 + t;
            if (q == 0)      { v0 = We[0 * H_]; v1 = We[1 * H_]; v2 = We[2 * H_]; v3 = We[3 * H_]; }
            else if (q == 1) { v0 = We[4 * H_]; v1 = We[5 * H_]; v2 = b1[e * H_ + f * 16 + t]; }
            W1F[e][f].h2[0] = pkrtz(v0, v1); W1F[e][f].h2[1] = pkrtz(v2, v3);
        }
        #pragma unroll
        for (int p = 0; p < 4; ++p) {
            int c0 = ((p >> 1) << 4) + q * 4 + ((p & 1) << 1);
            W2F[e][0].h2[p] = pkrtz(W2[(e * H_ + c0) * H_ + 0  + t], W2[(e * H_ + c0 + 1) * H_ + 0  + t]);
            W2F[e][1].h2[p] = pkrtz(W2[(e * H_ + c0) * H_ + 16 + t], W2[(e * H_ + c0 + 1) * H_ + 16 + t]);
            B2R[e].h2[p]    = pkrtz(b2[e * H_ + c0], b2[e * H_ + c0 + 1]);
            float v0 = 0.f, v1 = 0.f;
            if ((t >> 1) == e) {      // Y rows m=(e,o): this expert's rows only
                v0 = W3[(e * H_ + c0) * 2 + (t & 1)];
                v1 = W3[(e * H_ + c0 + 1) * 2 + (t & 1)];
            }
            W3F[e].h2[p] = pkrtz(v0, v1);
        }
    }

    // ---- persistent C-inits: bg2 (log2-domain) for the gate; b3 for all 16 Y rows m=(e,o)
    float4_t bg2F, b3F;
    #pragma unroll
    for (int r = 0; r < 4; ++r) {
        int m = q * 4 + r;
        bg2F[r] = (m < E_) ? bg2[m] * L2E : 0.f;
        b3F[r]  = b3[m];
    }
    const float4_t zero4 = {0.f, 0.f, 0.f, 0.f};

    // gate pull: lane(q,t) fetches ex[t,2q],ex[t,2q+1] from lane (q>>1)*16+t
    const int gsrc = ((((q >> 1) << 4) | t) << 2);

    const int tile0 = gw * tilesPerWave;

    // ---- per-lane x source (loop-invariant): quad0 reads x[t][0..3]; quads>=1 read x[t][4..5]
    const int xo1 = (q == 0) ? 0 : 4;
    const int xo2 = (q == 0) ? 2 : 4;
    const float* xq = x + ((size_t)tile0 * 16 + t) * DIN_;
    float2_t la = {0.f, 0.f}, lb = {0.f, 0.f};
    if (tile0 < nTiles) {
        la = *(const float2_t*)(xq + xo1);
        lb = *(const float2_t*)(xq + xo2);
    }

    HI onei; onei.h = pkrtz(1.f, 0.f);
    const bool isq0 = (q == 0);

    for (int it = 0; it < tilesPerWave; ++it) {
        const int tile = tile0 + it;
        if (tile >= nTiles) break;          // uniform per wave

        // ---- x B-fragment (K=16): q0:(x0..x3) q1:(x4,x5,1,dc) q2/q3: dc (A=0 there)
        H4U ux;
        ux.h2[0] = pkrtz(la[0], la[1]);
        HI hb; hb.h = pkrtz(lb[0], lb[1]);
        HI se; se.i = isq0 ? hb.i : onei.i;
        ux.h2[1] = se.h;
        const half4_t xB = ux.h4;

        // ---- prefetch next tile's x
        if ((it + 1) < tilesPerWave && (tile + 1) < nTiles) {
            const float* xn = xq + (size_t)(it + 1) * 16 * DIN_;
            la = *(const float2_t*)(xn + xo1);
            lb = *(const float2_t*)(xn + xo2);
        }

        // ---- gate (computed ONCE per tile now; logits already in log2 domain)
        float4_t hgLo = MFMA_K16(G1[0].h4, xB, zero4);
        float4_t hgHi = MFMA_K16(G1[1].h4, xB, zero4);
        H8U uh;
        uh.h2[0] = relu2(pkrtz(hgLo[0], hgLo[1]));
        uh.h2[1] = relu2(pkrtz(hgLo[2], hgLo[3]));
        uh.h2[2] = relu2(pkrtz(hgHi[0], hgHi[1]));
        uh.h2[3] = relu2(pkrtz(hgHi[2], hgHi[3]));
        float4_t gl = MFMA_K32(G2.h8, uh.h8, bg2F);

        // ---- softmax over 8 experts, no max-sub (|logit| bounded), normalization deferred
        float ex0 = __builtin_amdgcn_exp2f(gl[0]);
        float ex1 = __builtin_amdgcn_exp2f(gl[1]);
        float ex2 = __builtin_amdgcn_exp2f(gl[2]);
        float ex3 = __builtin_amdgcn_exp2f(gl[3]);
        float s = (ex0 + ex1) + (ex2 + ex3);
        s += __shfl_xor(s, 16);
        float rs = __builtin_amdgcn_rcpf(s);   // valid in quads 0-1; consumed by lanes<16 only
        HI pa, pb;
        pa.h = pkrtz(ex0, ex1);
        pb.h = pkrtz(ex2, ex3);
        int va = __builtin_amdgcn_ds_bpermute(gsrc, pa.i);
        int vb = __builtin_amdgcn_ds_bpermute(gsrc, pb.i);
        HI gsel; gsel.i = (q & 1) ? vb : va;       // lane(q,t): ex[t,2q], ex[t,2q+1]
        float ga = (float)gsel.h[0];
        float gb = (float)gsel.h[1];

        // ---- all 8 experts; Y rows m=(e,o) are disjoint across experts.
        //      Two accumulators halve the serial MFMA-accumulate chain.
        float4_t Ya = b3F, Yb = zero4;
        #pragma unroll
        for (int e = 0; e < EPW_; ++e) {
            float4_t lo = MFMA_K16(W1F[e][0].h4, xB, zero4);
            float4_t hi = MFMA_K16(W1F[e][1].h4, xB, zero4);
            H8U u1;
            u1.h2[0] = relu2(pkrtz(lo[0], lo[1]));
            u1.h2[1] = relu2(pkrtz(lo[2], lo[3]));
            u1.h2[2] = relu2(pkrtz(hi[0], hi[1]));
            u1.h2[3] = relu2(pkrtz(hi[2], hi[3]));
            float4_t lo2 = MFMA_K32(W2F[e][0].h8, u1.h8, zero4);
            float4_t hi2 = MFMA_K32(W2F[e][1].h8, u1.h8, zero4);
            H8U u2;
            u2.h2[0] = relu2(pkrtz(lo2[0], lo2[1]) + B2R[e].h2[0]);
            u2.h2[1] = relu2(pkrtz(lo2[2], lo2[3]) + B2R[e].h2[1]);
            u2.h2[2] = relu2(pkrtz(hi2[0], hi2[1]) + B2R[e].h2[2]);
            u2.h2[3] = relu2(pkrtz(hi2[2], hi2[3]) + B2R[e].h2[3]);
            if (e & 1) Yb = MFMA_K32(W3F[e].h8, u2.h8, Yb);
            else       Ya = MFMA_K32(W3F[e].h8, u2.h8, Ya);
        }

        // ---- gated partial: lane(q,t) holds Y rows m=4q+r -> experts {2q,2q+1}, o=r&1.
        //      ex-weighted (unnormalized), then sum over the 4 quads with shfl_xor. No LDS.
        float p0 = ga * (Ya[0] + Yb[0]) + gb * (Ya[2] + Yb[2]);
        float p1 = ga * (Ya[1] + Yb[1]) + gb * (Ya[3] + Yb[3]);
        p0 += __shfl_xor(p0, 16);
        p0 += __shfl_xor(p0, 32);
        p1 += __shfl_xor(p1, 16);
        p1 += __shfl_xor(p1, 32);

        if (lane < 16) {
            float2_t o = {p0 * rs, p1 * rs};
            *(float2_t*)(out + ((size_t)tile * 16 + t) * 2) = o;
        }
    }
}

extern "C" void kernel_launch(void* const* d_in, const int* in_sizes, int n_in,
                              void* d_out, int out_size, void* d_ws, size_t ws_size,
                              hipStream_t stream) {
    const float* x   = (const float*)d_in[0];
    const float* W1  = (const float*)d_in[1];
    const float* b1  = (const float*)d_in[2];
    const float* W2  = (const float*)d_in[3];
    const float* b2  = (const float*)d_in[4];
    const float* W3  = (const float*)d_in[5];
    const float* b3  = (const float*)d_in[6];
    const float* Wg1 = (const float*)d_in[7];
    const float* bg1 = (const float*)d_in[8];
    const float* Wg2 = (const float*)d_in[9];
    const float* bg2 = (const float*)d_in[10];
    float* out = (float*)d_out;

    const int B      = in_sizes[0] / DIN_;
    const int nTiles = (B + 15) / 16;
    // 512 blocks x 4 independent waves = 2048 waves = 2 waves/SIMD residency at ~220 VGPR.
    // Exact fill: nTiles (65536) / 2048 = 32 tiles/wave, zero tail, preamble amortized 32x.
    const int blocks = 512;
    const int wavesTotal = blocks * 4;
    const int tpw = (nTiles + wavesTotal - 1) / wavesTotal;

    moe_kernel<<<blocks, 256, 0, stream>>>(x, W1, b1, W2, b2, W3, b3,
                                           Wg1, bg1, Wg2, bg2, out, nTiles, tpw);
}

// Round 2
// 175.661 us; speedup vs baseline: 1.0095x; 1.0095x over previous
//
#include <hip/hip_runtime.h>

// MoE: out[b,:] = sum_e softmax(gate(x))[b,e] * (W3_e^T @ relu(W2_e^T @ relu(W1_e^T @ x_b + b1) + b2) + b3)
// Tokens-as-N MFMA. L1 uses 16x16x16 f16 (K=7 useful, k=4q+j). L2/L3/gate-L2 use 16x16x32 f16
// with K-permutation pi(q*8+j)=q*4+(j&3)+16*(j>>2) so C/D layout == next layer's B layout
// in-lane (HW-verified across R2-R9: absmax 0.0156).
// R10: R9 structure (1 wave owns a whole tile, all 8 experts, gate 1x, no LDS/no barriers) +
//      SPILL FIX. R9 bench showed VGPR_Count=128 vs ~220 demand: hipcc's occupancy heuristic
//      targeted 4 waves/SIMD and spilled ~100 regs (WRITE_SIZE 8->60 MB = preamble spill
//      stores; per-iter reloads gutted issue: MfmaUtil 16%). amdgpu_waves_per_eu(2,2) pins
//      the allocator at exactly 2 waves/EU = 256-VGPR budget -> zero spills. 512 blocks x 4
//      independent waves = 2048 waves = exact chip fill at 2 waves/SIMD.

typedef _Float16 half2_t __attribute__((ext_vector_type(2)));
typedef _Float16 half4_t __attribute__((ext_vector_type(4)));
typedef _Float16 half8_t __attribute__((ext_vector_type(8)));
typedef __fp16   fp16v2  __attribute__((ext_vector_type(2)));
typedef float  float4_t __attribute__((ext_vector_type(4)));
typedef float  float2_t __attribute__((ext_vector_type(2)));
typedef int    int2_t   __attribute__((ext_vector_type(2)));
typedef int    int4_t   __attribute__((ext_vector_type(4)));

#define MFMA_K32(A, B, C) __builtin_amdgcn_mfma_f32_16x16x32_f16((A), (B), (C), 0, 0, 0)
#define MFMA_K16(A, B, C) __builtin_amdgcn_mfma_f32_16x16x16f16((A), (B), (C), 0, 0, 0)

static constexpr int E_ = 8, DIN_ = 6, H_ = 32, EPW_ = 8;   // experts per wave (all of them)

union H8U { half2_t h2[4]; half8_t h8; int4_t i4; };
union H4U { half2_t h2[2]; half4_t h4; int2_t i2; };
union HI  { half2_t h; int i; };
union PKU { fp16v2 p; half2_t h; };

__device__ __forceinline__ half2_t pkrtz(float a, float b) {
    PKU u; u.p = __builtin_amdgcn_cvt_pkrtz(a, b);
    return u.h;
}

__device__ __forceinline__ half2_t relu2(half2_t v) {
    const half2_t z = {(_Float16)0.0f, (_Float16)0.0f};
    return __builtin_elementwise_max(v, z);
}

__global__ __launch_bounds__(256)
__attribute__((amdgpu_waves_per_eu(2, 2)))
void moe_kernel(
    const float* __restrict__ x,  const float* __restrict__ W1, const float* __restrict__ b1,
    const float* __restrict__ W2, const float* __restrict__ b2, const float* __restrict__ W3,
    const float* __restrict__ b3, const float* __restrict__ Wg1, const float* __restrict__ bg1,
    const float* __restrict__ Wg2, const float* __restrict__ bg2,
    float* __restrict__ out, int nTiles, int tilesPerWave)
{
    const int tid  = threadIdx.x;
    const int lane = tid & 63;
    const int t    = lane & 15;   // token slot
    const int q    = lane >> 4;   // K-quad / row-quad
    const int gw   = (blockIdx.x << 2) + (tid >> 6);   // global wave id (waves independent)

    const float L2E = 1.44269504f;

    // ---- gate L1 A-fragments (K=16, k=4q+j; slots 0..5 = x features, 6 = bias-as-1.0)
    H4U G1[2];
    #pragma unroll
    for (int f = 0; f < 2; ++f) {
        float v0 = 0.f, v1 = 0.f, v2 = 0.f, v3 = 0.f;
        if (q == 0) {
            v0 = Wg1[0 * H_ + f * 16 + t]; v1 = Wg1[1 * H_ + f * 16 + t];
            v2 = Wg1[2 * H_ + f * 16 + t]; v3 = Wg1[3 * H_ + f * 16 + t];
        } else if (q == 1) {
            v0 = Wg1[4 * H_ + f * 16 + t]; v1 = Wg1[5 * H_ + f * 16 + t];
            v2 = bg1[f * 16 + t];          v3 = 0.f;
        }
        G1[f].h2[0] = pkrtz(v0, v1); G1[f].h2[1] = pkrtz(v2, v3);
    }
    // ---- gate L2 A-fragment (K=32, pi layout), pre-scaled by log2(e) so logits are exp2-ready
    H8U G2;
    #pragma unroll
    for (int p = 0; p < 4; ++p) {
        int c0 = ((p >> 1) << 4) + q * 4 + ((p & 1) << 1);
        float v0 = (t < E_) ? Wg2[c0 * E_ + t] * L2E : 0.f;
        float v1 = (t < E_) ? Wg2[(c0 + 1) * E_ + t] * L2E : 0.f;
        G2.h2[p] = pkrtz(v0, v1);
    }

    // ---- ALL 8 experts: L1 (K16), L2 (K32 pi), L3 (K32 pi, block-diag rows), b2 pairs
    H4U W1F[EPW_][2];
    H8U W2F[EPW_][2], W3F[EPW_], B2R[EPW_];
    #pragma unroll
    for (int e = 0; e < EPW_; ++e) {
        #pragma unroll
        for (int f = 0; f < 2; ++f) {
            float v0 = 0.f, v1 = 0.f, v2 = 0.f, v3 = 0.f;
            const float* We = W1 + (size_t)e * DIN_ * H_ + f * 16 + t;
            if (q == 0)      { v0 = We[0 * H_]; v1 = We[1 * H_]; v2 = We[2 * H_]; v3 = We[3 * H_]; }
            else if (q == 1) { v0 = We[4 * H_]; v1 = We[5 * H_]; v2 = b1[e * H_ + f * 16 + t]; }
            W1F[e][f].h2[0] = pkrtz(v0, v1); W1F[e][f].h2[1] = pkrtz(v2, v3);
        }
        #pragma unroll
        for (int p = 0; p < 4; ++p) {
            int c0 = ((p >> 1) << 4) + q * 4 + ((p & 1) << 1);
            W2F[e][0].h2[p] = pkrtz(W2[(e * H_ + c0) * H_ + 0  + t], W2[(e * H_ + c0 + 1) * H_ + 0  + t]);
            W2F[e][1].h2[p] = pkrtz(W2[(e * H_ + c0) * H_ + 16 + t], W2[(e * H_ + c0 + 1) * H_ + 16 + t]);
            B2R[e].h2[p]    = pkrtz(b2[e * H_ + c0], b2[e * H_ + c0 + 1]);
            float v0 = 0.f, v1 = 0.f;
            if ((t >> 1) == e) {      // Y rows m=(e,o): this expert's rows only
                v0 = W3[(e * H_ + c0) * 2 + (t & 1)];
                v1 = W3[(e * H_ + c0 + 1) * 2 + (t & 1)];
            }
            W3F[e].h2[p] = pkrtz(v0, v1);
        }
    }

    // ---- persistent C-inits: bg2 (log2-domain) for the gate; b3 for all 16 Y rows m=(e,o)
    float4_t bg2F, b3F;
    #pragma unroll
    for (int r = 0; r < 4; ++r) {
        int m = q * 4 + r;
        bg2F[r] = (m < E_) ? bg2[m] * L2E : 0.f;
        b3F[r]  = b3[m];
    }
    const float4_t zero4 = {0.f, 0.f, 0.f, 0.f};

    // gate pull: lane(q,t) fetches ex[t,2q],ex[t,2q+1] from lane (q>>1)*16+t
    const int gsrc = ((((q >> 1) << 4) | t) << 2);

    const int tile0 = gw * tilesPerWave;

    // ---- per-lane x source (loop-invariant): quad0 reads x[t][0..3]; quads>=1 read x[t][4..5]
    const int xo1 = (q == 0) ? 0 : 4;
    const int xo2 = (q == 0) ? 2 : 4;
    const float* xq = x + ((size_t)tile0 * 16 + t) * DIN_;
    float2_t la = {0.f, 0.f}, lb = {0.f, 0.f};
    if (tile0 < nTiles) {
        la = *(const float2_t*)(xq + xo1);
        lb = *(const float2_t*)(xq + xo2);
    }

    HI onei; onei.h = pkrtz(1.f, 0.f);
    const bool isq0 = (q == 0);

    for (int it = 0; it < tilesPerWave; ++it) {
        const int tile = tile0 + it;
        if (tile >= nTiles) break;          // uniform per wave

        // ---- x B-fragment (K=16): q0:(x0..x3) q1:(x4,x5,1,dc) q2/q3: dc (A=0 there)
        H4U ux;
        ux.h2[0] = pkrtz(la[0], la[1]);
        HI hb; hb.h = pkrtz(lb[0], lb[1]);
        HI se; se.i = isq0 ? hb.i : onei.i;
        ux.h2[1] = se.h;
        const half4_t xB = ux.h4;

        // ---- prefetch next tile's x
        if ((it + 1) < tilesPerWave && (tile + 1) < nTiles) {
            const float* xn = xq + (size_t)(it + 1) * 16 * DIN_;
            la = *(const float2_t*)(xn + xo1);
            lb = *(const float2_t*)(xn + xo2);
        }

        // ---- gate (computed ONCE per tile; logits already in log2 domain)
        float4_t hgLo = MFMA_K16(G1[0].h4, xB, zero4);
        float4_t hgHi = MFMA_K16(G1[1].h4, xB, zero4);
        H8U uh;
        uh.h2[0] = relu2(pkrtz(hgLo[0], hgLo[1]));
        uh.h2[1] = relu2(pkrtz(hgLo[2], hgLo[3]));
        uh.h2[2] = relu2(pkrtz(hgHi[0], hgHi[1]));
        uh.h2[3] = relu2(pkrtz(hgHi[2], hgHi[3]));
        float4_t gl = MFMA_K32(G2.h8, uh.h8, bg2F);

        // ---- softmax over 8 experts, no max-sub (|logit| bounded), normalization deferred
        float ex0 = __builtin_amdgcn_exp2f(gl[0]);
        float ex1 = __builtin_amdgcn_exp2f(gl[1]);
        float ex2 = __builtin_amdgcn_exp2f(gl[2]);
        float ex3 = __builtin_amdgcn_exp2f(gl[3]);
        float s = (ex0 + ex1) + (ex2 + ex3);
        s += __shfl_xor(s, 16);
        float rs = __builtin_amdgcn_rcpf(s);   // valid in quads 0-1; consumed by lanes<16 only
        HI pa, pb;
        pa.h = pkrtz(ex0, ex1);
        pb.h = pkrtz(ex2, ex3);
        int va = __builtin_amdgcn_ds_bpermute(gsrc, pa.i);
        int vb = __builtin_amdgcn_ds_bpermute(gsrc, pb.i);
        HI gsel; gsel.i = (q & 1) ? vb : va;       // lane(q,t): ex[t,2q], ex[t,2q+1]
        float ga = (float)gsel.h[0];
        float gb = (float)gsel.h[1];

        // ---- all 8 experts; Y rows m=(e,o) are disjoint across experts.
        //      Two accumulators halve the serial MFMA-accumulate chain.
        float4_t Ya = b3F, Yb = zero4;
        #pragma unroll
        for (int e = 0; e < EPW_; ++e) {
            float4_t lo = MFMA_K16(W1F[e][0].h4, xB, zero4);
            float4_t hi = MFMA_K16(W1F[e][1].h4, xB, zero4);
            H8U u1;
            u1.h2[0] = relu2(pkrtz(lo[0], lo[1]));
            u1.h2[1] = relu2(pkrtz(lo[2], lo[3]));
            u1.h2[2] = relu2(pkrtz(hi[0], hi[1]));
            u1.h2[3] = relu2(pkrtz(hi[2], hi[3]));
            float4_t lo2 = MFMA_K32(W2F[e][0].h8, u1.h8, zero4);
            float4_t hi2 = MFMA_K32(W2F[e][1].h8, u1.h8, zero4);
            H8U u2;
            u2.h2[0] = relu2(pkrtz(lo2[0], lo2[1]) + B2R[e].h2[0]);
            u2.h2[1] = relu2(pkrtz(lo2[2], lo2[3]) + B2R[e].h2[1]);
            u2.h2[2] = relu2(pkrtz(hi2[0], hi2[1]) + B2R[e].h2[2]);
            u2.h2[3] = relu2(pkrtz(hi2[2], hi2[3]) + B2R[e].h2[3]);
            if (e & 1) Yb = MFMA_K32(W3F[e].h8, u2.h8, Yb);
            else       Ya = MFMA_K32(W3F[e].h8, u2.h8, Ya);
        }

        // ---- gated partial: lane(q,t) holds Y rows m=4q+r -> experts {2q,2q+1}, o=r&1.
        //      ex-weighted (unnormalized), then sum over the 4 quads with shfl_xor. No LDS.
        float p0 = ga * (Ya[0] + Yb[0]) + gb * (Ya[2] + Yb[2]);
        float p1 = ga * (Ya[1] + Yb[1]) + gb * (Ya[3] + Yb[3]);
        p0 += __shfl_xor(p0, 16);
        p0 += __shfl_xor(p0, 32);
        p1 += __shfl_xor(p1, 16);
        p1 += __shfl_xor(p1, 32);

        if (lane < 16) {
            float2_t o = {p0 * rs, p1 * rs};
            *(float2_t*)(out + ((size_t)tile * 16 + t) * 2) = o;
        }
    }
}

extern "C" void kernel_launch(void* const* d_in, const int* in_sizes, int n_in,
                              void* d_out, int out_size, void* d_ws, size_t ws_size,
                              hipStream_t stream) {
    const float* x   = (const float*)d_in[0];
    const float* W1  = (const float*)d_in[1];
    const float* b1  = (const float*)d_in[2];
    const float* W2  = (const float*)d_in[3];
    const float* b2  = (const float*)d_in[4];
    const float* W3  = (const float*)d_in[5];
    const float* b3  = (const float*)d_in[6];
    const float* Wg1 = (const float*)d_in[7];
    const float* bg1 = (const float*)d_in[8];
    const float* Wg2 = (const float*)d_in[9];
    const float* bg2 = (const float*)d_in[10];
    float* out = (float*)d_out;

    const int B      = in_sizes[0] / DIN_;
    const int nTiles = (B + 15) / 16;
    // 512 blocks x 4 independent waves = 2048 waves = exact chip fill at 2 waves/SIMD
    // (pinned by amdgpu_waves_per_eu(2,2): 256-VGPR budget, zero spills).
    // nTiles (65536) / 2048 = 32 tiles/wave, zero tail, preamble amortized 32x.
    const int blocks = 512;
    const int wavesTotal = blocks * 4;
    const int tpw = (nTiles + wavesTotal - 1) / wavesTotal;

    moe_kernel<<<blocks, 256, 0, stream>>>(x, W1, b1, W2, b2, W3, b3,
                                           Wg1, bg1, Wg2, bg2, out, nTiles, tpw);
}